// Round 7
// baseline (1684.271 us; speedup 1.0000x reference)
//
#include <hip/hip_runtime.h>
#include <hip/hip_bf16.h>

typedef short bf16x8 __attribute__((ext_vector_type(8)));
typedef float f32x4 __attribute__((ext_vector_type(4)));
typedef ushort ushort8_t __attribute__((ext_vector_type(8)));

__device__ __forceinline__ float bf2f(ushort u) {
    union { unsigned int i; float f; } c; c.i = ((unsigned int)u) << 16; return c.f;
}
__device__ __forceinline__ ushort f2bf(float f) {
    union { float f; unsigned int i; } c; c.f = f;
    unsigned int x = c.i;
    return (ushort)((x + 0x7fffu + ((x >> 16) & 1u)) >> 16);  // RNE
}

#define GLOAD_LDS16(g, l) __builtin_amdgcn_global_load_lds( \
    (const __attribute__((address_space(1))) unsigned int*)(g), \
    (__attribute__((address_space(3))) unsigned int*)(l), 16, 0, 0)

// ---------------- prep: fp32 -> bf16 (vectorized) ----------------
__global__ __launch_bounds__(256) void k_cvt_bf16(const float* __restrict__ in,
                                                  ushort* __restrict__ out, int n4) {
    int i = blockIdx.x * 256 + threadIdx.x;
    if (i < n4) {
        float4 v = ((const float4*)in)[i];
        ushort4 o;
        o.x = f2bf(v.x); o.y = f2bf(v.y); o.z = f2bf(v.z); o.w = f2bf(v.w);
        ((ushort4*)out)[i] = o;
    }
}

// ---------------- prep: [K][N] fp32 -> [N][K] bf16 ----------------
__global__ __launch_bounds__(256) void k_transpose_cvt(const float* __restrict__ in,
                                                       ushort* __restrict__ out,
                                                       int K, int N) {
    __shared__ float tile[32][33];
    int n0 = blockIdx.x * 32, k0 = blockIdx.y * 32;
    int tx = threadIdx.x, ty = threadIdx.y;  // blockDim (32,8)
    #pragma unroll
    for (int i = 0; i < 32; i += 8)
        tile[ty + i][tx] = in[(size_t)(k0 + ty + i) * N + n0 + tx];
    __syncthreads();
    #pragma unroll
    for (int i = 0; i < 32; i += 8)
        out[(size_t)(n0 + ty + i) * K + k0 + tx] = f2bf(tile[tx][ty + i]);
}

// ============ 256x256 GEMM, BK=32, 64KB LDS -> 2 blocks/CU (K=1024) ======
// 8 waves (2Mx4N), wave tile 128x64.  LDS: buf[2] x {A[256][32], B[256][32]}
// = 64 KB, so TWO independent blocks co-reside per CU; each block's
// drain/barrier stalls are filled by the other block's MFMAs (the m114
// cross-block overlap a 128KB kernel physically cannot get).
// Race-free proof: per iter, reads -> lgkmcnt(0)+sched_barrier (rule 18) ->
// s_barrier certifies ALL waves' reads serviced before any wave's stage
// overwrites buf[cur] (WAR).  vmcnt(4) before end-barrier certifies tile
// t+1's loads (issued iter t-1) landed across all waves (RAW; 4 = this
// iter's in-flight stage).  Tail: t=30 uses vmcnt(0).  Swizzle: 16B chunk
// ^= (row>>1)&3 on pre-swizzled global source + ds_read addr (verified
// SQ_LDS_BANK_CONFLICT == 0; region geometry unchanged from r3).

#define LDSA(c) (lds + (c)*32768)
#define LDSB(c) (lds + (c)*32768 + 16384)
#define STAGE_A(c,col) do { \
    GLOAD_LDS16(gA0 + (col), LDSA(c) + wave*1024); \
    GLOAD_LDS16(gA1 + (col), LDSA(c) + 8192 + wave*1024); } while(0)
#define STAGE_B(c,col) do { \
    GLOAD_LDS16(gB0 + (col), LDSB(c) + wave*1024); \
    GLOAD_LDS16(gB1 + (col), LDSB(c) + 8192 + wave*1024); } while(0)

#define BAR __builtin_amdgcn_s_barrier()
#define SB0 __builtin_amdgcn_sched_barrier(0)
#define LGK0 asm volatile("s_waitcnt lgkmcnt(0)")
#define VM4 asm volatile("s_waitcnt vmcnt(4)")
#define VM0 asm volatile("s_waitcnt vmcnt(0)")

template<bool OUT_BF16>
__global__ __launch_bounds__(512, 4) void k_gemm256(const ushort* __restrict__ A,
                                                    const ushort* __restrict__ Bt,
                                                    const float* __restrict__ bias,
                                                    void* __restrict__ Cout,
                                                    int N, int NTN) {
    __shared__ __align__(16) char lds[65536];
    const int K = 1024, NT = 32;
    const int tid = threadIdx.x;
    const int wave = tid >> 6, lane = tid & 63;
    const int wr = wave >> 2, wc = wave & 3;
    const int r = lane & 15, q = lane >> 4;

    // bijective XCD swizzle (gridDim.x % 8 == 0)
    const int cpx = gridDim.x >> 3, wg = blockIdx.x;
    const int swz = (wg & 7) * cpx + (wg >> 3);
    const int tm = swz / NTN, tn = swz - tm * NTN;
    const int bm = tm * 256, bn = tn * 256;

    // staging lane pointers (source pre-swizzled: chunk ^= (row>>1)&3)
    const int srow = tid >> 2;                      // 0..127
    const int c16l = (tid & 3) ^ ((srow >> 1) & 3);
    const ushort* gA0 = A  + (size_t)(bm + srow) * K + c16l * 8;
    const ushort* gA1 = gA0 + (size_t)128 * K;
    const ushort* gB0 = Bt + (size_t)(bn + srow) * K + c16l * 8;
    const ushort* gB1 = gB0 + (size_t)128 * K;

    // swizzled ds_read offsets: chunk = q ^ ((row>>1)&3)
    const int chunkx = ((q ^ ((r >> 1) & 3)) << 4);
    const int aoff = (wr * 128 + r) * 64 + chunkx;
    const int boff = (wc * 64 + r) * 64 + chunkx;

    f32x4 acc[8][4];
    #pragma unroll
    for (int m = 0; m < 8; ++m)
        #pragma unroll
        for (int n = 0; n < 4; ++n)
            acc[m][n] = (f32x4){0.f, 0.f, 0.f, 0.f};
    bf16x8 af[8], bfr[4];

    // prologue: stage tiles 0 and 1; vmcnt(4) retires tile 0's 4 loads.
    STAGE_A(0, 0);  STAGE_B(0, 0);
    STAGE_A(1, 32); STAGE_B(1, 32);
    VM4; BAR; SB0;

    #pragma unroll 2
    for (int t = 0; t < NT; ++t) {
        const int c = t & 1;
        const char* pA = LDSA(c) + aoff;
        const char* pB = LDSB(c) + boff;
        #pragma unroll
        for (int m = 0; m < 8; ++m) af[m] = *(const bf16x8*)(pA + m * 1024);
        #pragma unroll
        for (int n = 0; n < 4; ++n) bfr[n] = *(const bf16x8*)(pB + n * 1024);
        LGK0; SB0;          // reads serviced (own wave); rule-18 fence
        BAR;                // all waves done reading buf[c] -> WAR safe
        if (t < NT - 2) { STAGE_A(c, (t + 2) * 32); STAGE_B(c, (t + 2) * 32); }
        __builtin_amdgcn_s_setprio(1);
        #pragma unroll
        for (int m = 0; m < 8; ++m)
            #pragma unroll
            for (int n = 0; n < 4; ++n)
                acc[m][n] = __builtin_amdgcn_mfma_f32_16x16x32_bf16(af[m], bfr[n], acc[m][n], 0, 0, 0);
        __builtin_amdgcn_s_setprio(0);
        if (t < NT - 2) VM4; else if (t == NT - 2) VM0;  // tile t+1 landed (RAW)
        BAR; SB0;
    }

    float* Cf = (float*)Cout;
    ushort* Cb = (ushort*)Cout;
    #pragma unroll
    for (int m = 0; m < 8; ++m) {
        int row0 = bm + wr * 128 + m * 16 + q * 4;
        #pragma unroll
        for (int n = 0; n < 4; ++n) {
            int col = bn + wc * 64 + n * 16 + r;
            float bv = bias[col];
            #pragma unroll
            for (int j = 0; j < 4; ++j) {
                float v = acc[m][n][j] + bv;
                if (OUT_BF16) Cb[(size_t)(row0 + j) * N + col] = f2bf(v);
                else          Cf[(size_t)(row0 + j) * N + col] = v;
            }
        }
    }
}

// ---------------- per-token head-mixing attention, MFMA, 1 wave/token ----
// qkv row layout: col = h*192 + {0..63 q, 64..127 k, 128..191 v}
// Swapped QK^T: S^T = mfma16x16x32(A=K, B=Q): lane(r=l&15,g=l>>4) holds
// S[qh=r][kh=4g+j].  Softmax over kh: in-lane (4) + shfl_xor 16,32.
// PV via mfma16x16x32 with K padded to 32: A-frag lane needs P[r][8g+j]
// (j=0..7, zero for g>=2) gathered with 8 shuffles; B-frag = V[kh][d].
__global__ __launch_bounds__(256) void k_attn_mfma(const ushort* __restrict__ qkv,
                                                   ushort* __restrict__ ctx) {
    const int lane = threadIdx.x & 63;
    const size_t tok = (size_t)blockIdx.x * 4 + (threadIdx.x >> 6);
    const ushort* row = qkv + tok * 3072;
    const int r = lane & 15, g = lane >> 4;

    bf16x8 ka[2], qb[2];
    #pragma unroll
    for (int c = 0; c < 2; ++c) {
        ka[c] = *(const bf16x8*)(row + r * 192 + 64 + c * 32 + g * 8);  // K[r][d]
        qb[c] = *(const bf16x8*)(row + r * 192 +      c * 32 + g * 8);  // Q[r][d]
    }
    f32x4 st = (f32x4){0.f, 0.f, 0.f, 0.f};
    st = __builtin_amdgcn_mfma_f32_16x16x32_bf16(ka[0], qb[0], st, 0, 0, 0);
    st = __builtin_amdgcn_mfma_f32_16x16x32_bf16(ka[1], qb[1], st, 0, 0, 0);

    float s[4];
    #pragma unroll
    for (int j = 0; j < 4; ++j) s[j] = st[j] * 0.125f;
    float m = fmaxf(fmaxf(s[0], s[1]), fmaxf(s[2], s[3]));
    m = fmaxf(m, __shfl_xor(m, 16));
    m = fmaxf(m, __shfl_xor(m, 32));
    float p[4], sum = 0.f;
    #pragma unroll
    for (int j = 0; j < 4; ++j) { p[j] = __expf(s[j] - m); sum += p[j]; }
    sum += __shfl_xor(sum, 16);
    sum += __shfl_xor(sum, 32);
    float inv = 1.f / sum;
    #pragma unroll
    for (int j = 0; j < 4; ++j) p[j] *= inv;

    // gather A-frag: lane needs P[r][8g+j]; source lane r+32g (j0-3), +16 (j4-7)
    const bool gok = (g < 2);
    const int src0 = (r + 32 * g) & 63, src1 = (src0 + 16) & 63;
    bf16x8 pa;
    #pragma unroll
    for (int j = 0; j < 4; ++j) {
        float a0 = __shfl(p[j], src0, 64);
        float a1 = __shfl(p[j], src1, 64);
        pa[j]     = (short)(gok ? f2bf(a0) : (ushort)0);
        pa[4 + j] = (short)(gok ? f2bf(a1) : (ushort)0);
    }

    #pragma unroll
    for (int db = 0; db < 4; ++db) {
        bf16x8 vb;
        #pragma unroll
        for (int j = 0; j < 8; ++j)
            vb[j] = (short)(gok ? row[(g * 8 + j) * 192 + 128 + db * 16 + r] : (ushort)0);
        f32x4 o = (f32x4){0.f, 0.f, 0.f, 0.f};
        o = __builtin_amdgcn_mfma_f32_16x16x32_bf16(pa, vb, o, 0, 0, 0);
        #pragma unroll
        for (int j = 0; j < 4; ++j)
            ctx[tok * 1024 + (4 * g + j) * 64 + db * 16 + r] = f2bf(o[j]);
    }
}

extern "C" void kernel_launch(void* const* d_in, const int* in_sizes, int n_in,
                              void* d_out, int out_size, void* d_ws, size_t ws_size,
                              hipStream_t stream) {
    const float* x     = (const float*)d_in[0];
    const float* W_qkv = (const float*)d_in[1];
    const float* b_qkv = (const float*)d_in[2];
    const float* W_out = (const float*)d_in[3];
    const float* b_out = (const float*)d_in[4];

    const int M = 16384, D = 1024, N3 = 3072;

    ushort* xb   = (ushort*)d_ws;
    ushort* wqkT = xb + (size_t)M * D;
    ushort* woT  = wqkT + (size_t)N3 * D;
    ushort* qkv  = woT + (size_t)D * D;
    ushort* ctx  = xb;  // xb dead after GEMM1; reuse for context

    hipLaunchKernelGGL(k_cvt_bf16, dim3((M * D / 4 + 255) / 256), dim3(256), 0, stream,
                       x, xb, M * D / 4);
    hipLaunchKernelGGL(k_transpose_cvt, dim3(N3 / 32, D / 32), dim3(32, 8), 0, stream,
                       W_qkv, wqkT, D, N3);
    hipLaunchKernelGGL(k_transpose_cvt, dim3(D / 32, D / 32), dim3(32, 8), 0, stream,
                       W_out, woT, D, D);
    hipLaunchKernelGGL((k_gemm256<true>), dim3((N3 / 256) * (M / 256)), dim3(512), 0, stream,
                       xb, wqkT, b_qkv, (void*)qkv, N3, N3 / 256);
    hipLaunchKernelGGL(k_attn_mfma, dim3(M / 4), dim3(256), 0, stream, qkv, ctx);
    hipLaunchKernelGGL((k_gemm256<false>), dim3((D / 256) * (M / 256)), dim3(512), 0, stream,
                       ctx, woT, b_out, d_out, D, D / 256);
}

// Round 8
// 201.444 us; speedup vs baseline: 8.3610x; 8.3610x over previous
//
#include <hip/hip_runtime.h>
#include <hip/hip_bf16.h>

typedef short bf16x8 __attribute__((ext_vector_type(8)));
typedef float f32x4 __attribute__((ext_vector_type(4)));
typedef ushort ushort8_t __attribute__((ext_vector_type(8)));

__device__ __forceinline__ float bf2f(ushort u) {
    union { unsigned int i; float f; } c; c.i = ((unsigned int)u) << 16; return c.f;
}
__device__ __forceinline__ ushort f2bf(float f) {
    union { float f; unsigned int i; } c; c.f = f;
    unsigned int x = c.i;
    return (ushort)((x + 0x7fffu + ((x >> 16) & 1u)) >> 16);  // RNE
}

#define GLOAD_LDS16(g, l) __builtin_amdgcn_global_load_lds( \
    (const __attribute__((address_space(1))) unsigned int*)(g), \
    (__attribute__((address_space(3))) unsigned int*)(l), 16, 0, 0)

// ---------------- prep: fp32 -> bf16 (vectorized) ----------------
__global__ __launch_bounds__(256) void k_cvt_bf16(const float* __restrict__ in,
                                                  ushort* __restrict__ out, int n4) {
    int i = blockIdx.x * 256 + threadIdx.x;
    if (i < n4) {
        float4 v = ((const float4*)in)[i];
        ushort4 o;
        o.x = f2bf(v.x); o.y = f2bf(v.y); o.z = f2bf(v.z); o.w = f2bf(v.w);
        ((ushort4*)out)[i] = o;
    }
}

// ---------------- prep: [K][N] fp32 -> [N][K] bf16 ----------------
__global__ __launch_bounds__(256) void k_transpose_cvt(const float* __restrict__ in,
                                                       ushort* __restrict__ out,
                                                       int K, int N) {
    __shared__ float tile[32][33];
    int n0 = blockIdx.x * 32, k0 = blockIdx.y * 32;
    int tx = threadIdx.x, ty = threadIdx.y;  // blockDim (32,8)
    #pragma unroll
    for (int i = 0; i < 32; i += 8)
        tile[ty + i][tx] = in[(size_t)(k0 + ty + i) * N + n0 + tx];
    __syncthreads();
    #pragma unroll
    for (int i = 0; i < 32; i += 8)
        out[(size_t)(n0 + ty + i) * K + k0 + tx] = f2bf(tile[tx][ty + i]);
}

// ========== 256x256 8-phase GEMM, ONE barrier per phase (K=1024) ==========
// 8 waves (2Mx4N), wave tile 128x64, BK=64, LDS 128KB (r3 geometry, verified
// SQ_LDS_BANK_CONFLICT == 0).  r3's 41% MfmaUtil limiter was 16 barriers/iter
// forcing LDS-service to serialize with MFMA inside each phase.  This version
// merges to ONE barrier/phase: {reads; stage; MFMA; SB0; vm; BAR; SB0}.
// WAR proof: every ds_read is consumed by same-phase MFMA (compiler's counted
// lgkm waits complete it before this phase's BAR); every region is re-staged
// >=2 phases after its last read, so all readers are >=1 barrier ahead of the
// overwrite.  RAW proof: vm values/placement identical to r3's passing
// schedule -- VM10 at ph2/4/6/8 leaves exactly {last 5 stage-units} in
// flight, certifying the region read 2 phases later; LAST iter drains at ph2.
// sched_barrier(0) at phase edges stops cross-barrier code motion (rule 18).

#define LDSA(c,kk) (lds + (c)*65536 + (kk)*16384)
#define LDSB(c,kk) (lds + (c)*65536 + 32768 + (kk)*16384)
#define STAGE_A(c,kk,col) do { \
    GLOAD_LDS16(gA0 + (col), LDSA(c,kk) + wave*1024); \
    GLOAD_LDS16(gA1 + (col), LDSA(c,kk) + 8192 + wave*1024); } while(0)
#define STAGE_B(c,kk,col) do { \
    GLOAD_LDS16(gB0 + (col), LDSB(c,kk) + wave*1024); \
    GLOAD_LDS16(gB1 + (col), LDSB(c,kk) + 8192 + wave*1024); } while(0)
#define READ_A8(c,kk) do { const char* _p = LDSA(c,kk) + aoff; \
    _Pragma("unroll") for (int m = 0; m < 8; ++m) af[m] = *(const bf16x8*)(_p + m*1024); } while(0)
#define READ_B2(c,kk,n0) do { const char* _p = LDSB(c,kk) + boff; \
    bfr[n0] = *(const bf16x8*)(_p + (n0)*1024); \
    bfr[(n0)+1] = *(const bf16x8*)(_p + ((n0)+1)*1024); } while(0)
#define MF16(n0) do { __builtin_amdgcn_s_setprio(1); \
    _Pragma("unroll") for (int m = 0; m < 8; ++m) { \
    acc[m][n0]     = __builtin_amdgcn_mfma_f32_16x16x32_bf16(af[m], bfr[n0],     acc[m][n0],     0,0,0); \
    acc[m][(n0)+1] = __builtin_amdgcn_mfma_f32_16x16x32_bf16(af[m], bfr[(n0)+1], acc[m][(n0)+1], 0,0,0); } \
    __builtin_amdgcn_s_setprio(0); } while(0)

#define BAR __builtin_amdgcn_s_barrier()
#define SB0 __builtin_amdgcn_sched_barrier(0)
#define VM10 asm volatile("s_waitcnt vmcnt(10)")
#define VM0  asm volatile("s_waitcnt vmcnt(0)")

// One phase: [reads (same-phase-consumed)][stage][MFMA][SB0][vm][BAR][SB0]
#define PH1(reads, stage, mf, vm) do { reads; stage; mf; SB0; vm; BAR; SB0; } while(0)

#define ITERX(kb, LAST) do { \
  /*1*/ PH1( { READ_A8(0,0); READ_B2(0,0,0); }, STAGE_B(1,1,(kb)+96),              MF16(0), ); \
  /*2*/ PH1( { READ_B2(0,0,2); },               if(!(LAST)) STAGE_A(0,0,(kb)+128), MF16(2), if(LAST) VM0; else VM10 ); \
  /*3*/ PH1( { READ_A8(0,1); READ_B2(0,1,0); }, if(!(LAST)) STAGE_B(0,0,(kb)+128), MF16(0), ); \
  /*4*/ PH1( { READ_B2(0,1,2); },               if(!(LAST)) STAGE_A(0,1,(kb)+160), MF16(2), if(!(LAST)) VM10 ); \
  /*5*/ PH1( { READ_A8(1,0); READ_B2(1,0,0); }, if(!(LAST)) STAGE_B(0,1,(kb)+160), MF16(0), ); \
  /*6*/ PH1( { READ_B2(1,0,2); },               if(!(LAST)) STAGE_A(1,0,(kb)+192), MF16(2), if(!(LAST)) VM10 ); \
  /*7*/ PH1( { READ_A8(1,1); READ_B2(1,1,0); }, if(!(LAST)) STAGE_B(1,0,(kb)+192), MF16(0), ); \
  /*8*/ PH1( { READ_B2(1,1,2); },               if(!(LAST)) STAGE_A(1,1,(kb)+224), MF16(2), if(!(LAST)) VM10 ); \
} while(0)

template<bool OUT_BF16>
__global__ __launch_bounds__(512, 2) void k_gemm256(const ushort* __restrict__ A,
                                                    const ushort* __restrict__ Bt,
                                                    const float* __restrict__ bias,
                                                    void* __restrict__ Cout,
                                                    int N, int NTN) {
    __shared__ __align__(16) char lds[131072];
    const int K = 1024;
    const int tid = threadIdx.x;
    const int wave = tid >> 6, lane = tid & 63;
    const int wr = wave >> 2, wc = wave & 3;
    const int r = lane & 15, q = lane >> 4;

    // bijective XCD swizzle (gridDim.x % 8 == 0)
    const int cpx = gridDim.x >> 3, wg = blockIdx.x;
    const int swz = (wg & 7) * cpx + (wg >> 3);
    const int tm = swz / NTN, tn = swz - tm * NTN;
    const int bm = tm * 256, bn = tn * 256;

    // staging lane pointers (source pre-swizzled: chunk ^= (row>>1)&3)
    const int srow = tid >> 2;                      // 0..127
    const int c16l = (tid & 3) ^ ((srow >> 1) & 3);
    const ushort* gA0 = A  + (size_t)(bm + srow) * K + c16l * 8;
    const ushort* gA1 = gA0 + (size_t)128 * K;
    const ushort* gB0 = Bt + (size_t)(bn + srow) * K + c16l * 8;
    const ushort* gB1 = gB0 + (size_t)128 * K;

    // swizzled ds_read offsets: chunk = q ^ ((row>>1)&3)
    const int chunkx = ((q ^ ((r >> 1) & 3)) << 4);
    const int aoff = (wr * 128 + r) * 64 + chunkx;
    const int boff = (wc * 64 + r) * 64 + chunkx;

    f32x4 acc[8][4];
    #pragma unroll
    for (int m = 0; m < 8; ++m)
        #pragma unroll
        for (int n = 0; n < 4; ++n)
            acc[m][n] = (f32x4){0.f, 0.f, 0.f, 0.f};
    bf16x8 af[8], bfr[4];

    // prologue: stage A00,B00,A01,B01,A10,B10,A11 (14 loads); VM10 retires
    // the first 4 (= A00,B00) needed by iter0 phase 1.
    STAGE_A(0,0,0);  STAGE_B(0,0,0);
    STAGE_A(0,1,32); STAGE_B(0,1,32);
    STAGE_A(1,0,64); STAGE_B(1,0,64);
    STAGE_A(1,1,96);
    VM10; BAR; SB0;

    #pragma unroll 1
    for (int i = 0; i < 7; ++i) { ITERX(i * 128, 0); }
    ITERX(896, 1);

    float* Cf = (float*)Cout;
    ushort* Cb = (ushort*)Cout;
    #pragma unroll
    for (int m = 0; m < 8; ++m) {
        int row0 = bm + wr * 128 + m * 16 + q * 4;
        #pragma unroll
        for (int n = 0; n < 4; ++n) {
            int col = bn + wc * 64 + n * 16 + r;
            float bv = bias[col];
            #pragma unroll
            for (int j = 0; j < 4; ++j) {
                float v = acc[m][n][j] + bv;
                if (OUT_BF16) Cb[(size_t)(row0 + j) * N + col] = f2bf(v);
                else          Cf[(size_t)(row0 + j) * N + col] = v;
            }
        }
    }
}

// ---------------- per-token head-mixing attention, MFMA, 1 wave/token ----
// qkv row layout: col = h*192 + {0..63 q, 64..127 k, 128..191 v}
// Swapped QK^T: S^T = mfma16x16x32(A=K, B=Q): lane(r=l&15,g=l>>4) holds
// S[qh=r][kh=4g+j].  Softmax over kh: in-lane (4) + shfl_xor 16,32.
// PV via mfma16x16x32 with K padded to 32: A-frag lane needs P[r][8g+j]
// (j=0..7, zero for g>=2) gathered with 8 shuffles; B-frag = V[kh][d].
__global__ __launch_bounds__(256) void k_attn_mfma(const ushort* __restrict__ qkv,
                                                   ushort* __restrict__ ctx) {
    const int lane = threadIdx.x & 63;
    const size_t tok = (size_t)blockIdx.x * 4 + (threadIdx.x >> 6);
    const ushort* row = qkv + tok * 3072;
    const int r = lane & 15, g = lane >> 4;

    bf16x8 ka[2], qb[2];
    #pragma unroll
    for (int c = 0; c < 2; ++c) {
        ka[c] = *(const bf16x8*)(row + r * 192 + 64 + c * 32 + g * 8);  // K[r][d]
        qb[c] = *(const bf16x8*)(row + r * 192 +      c * 32 + g * 8);  // Q[r][d]
    }
    f32x4 st = (f32x4){0.f, 0.f, 0.f, 0.f};
    st = __builtin_amdgcn_mfma_f32_16x16x32_bf16(ka[0], qb[0], st, 0, 0, 0);
    st = __builtin_amdgcn_mfma_f32_16x16x32_bf16(ka[1], qb[1], st, 0, 0, 0);

    float s[4];
    #pragma unroll
    for (int j = 0; j < 4; ++j) s[j] = st[j] * 0.125f;
    float m = fmaxf(fmaxf(s[0], s[1]), fmaxf(s[2], s[3]));
    m = fmaxf(m, __shfl_xor(m, 16));
    m = fmaxf(m, __shfl_xor(m, 32));
    float p[4], sum = 0.f;
    #pragma unroll
    for (int j = 0; j < 4; ++j) { p[j] = __expf(s[j] - m); sum += p[j]; }
    sum += __shfl_xor(sum, 16);
    sum += __shfl_xor(sum, 32);
    float inv = 1.f / sum;
    #pragma unroll
    for (int j = 0; j < 4; ++j) p[j] *= inv;

    // gather A-frag: lane needs P[r][8g+j]; source lane r+32g (j0-3), +16 (j4-7)
    const bool gok = (g < 2);
    const int src0 = (r + 32 * g) & 63, src1 = (src0 + 16) & 63;
    bf16x8 pa;
    #pragma unroll
    for (int j = 0; j < 4; ++j) {
        float a0 = __shfl(p[j], src0, 64);
        float a1 = __shfl(p[j], src1, 64);
        pa[j]     = (short)(gok ? f2bf(a0) : (ushort)0);
        pa[4 + j] = (short)(gok ? f2bf(a1) : (ushort)0);
    }

    #pragma unroll
    for (int db = 0; db < 4; ++db) {
        bf16x8 vb;
        #pragma unroll
        for (int j = 0; j < 8; ++j)
            vb[j] = (short)(gok ? row[(g * 8 + j) * 192 + 128 + db * 16 + r] : (ushort)0);
        f32x4 o = (f32x4){0.f, 0.f, 0.f, 0.f};
        o = __builtin_amdgcn_mfma_f32_16x16x32_bf16(pa, vb, o, 0, 0, 0);
        #pragma unroll
        for (int j = 0; j < 4; ++j)
            ctx[tok * 1024 + (4 * g + j) * 64 + db * 16 + r] = f2bf(o[j]);
    }
}

extern "C" void kernel_launch(void* const* d_in, const int* in_sizes, int n_in,
                              void* d_out, int out_size, void* d_ws, size_t ws_size,
                              hipStream_t stream) {
    const float* x     = (const float*)d_in[0];
    const float* W_qkv = (const float*)d_in[1];
    const float* b_qkv = (const float*)d_in[2];
    const float* W_out = (const float*)d_in[3];
    const float* b_out = (const float*)d_in[4];

    const int M = 16384, D = 1024, N3 = 3072;

    ushort* xb   = (ushort*)d_ws;
    ushort* wqkT = xb + (size_t)M * D;
    ushort* woT  = wqkT + (size_t)N3 * D;
    ushort* qkv  = woT + (size_t)D * D;
    ushort* ctx  = xb;  // xb dead after GEMM1; reuse for context

    hipLaunchKernelGGL(k_cvt_bf16, dim3((M * D / 4 + 255) / 256), dim3(256), 0, stream,
                       x, xb, M * D / 4);
    hipLaunchKernelGGL(k_transpose_cvt, dim3(N3 / 32, D / 32), dim3(32, 8), 0, stream,
                       W_qkv, wqkT, D, N3);
    hipLaunchKernelGGL(k_transpose_cvt, dim3(D / 32, D / 32), dim3(32, 8), 0, stream,
                       W_out, woT, D, D);
    hipLaunchKernelGGL((k_gemm256<true>), dim3((N3 / 256) * (M / 256)), dim3(512), 0, stream,
                       xb, wqkT, b_qkv, (void*)qkv, N3, N3 / 256);
    hipLaunchKernelGGL(k_attn_mfma, dim3(M / 4), dim3(256), 0, stream, qkv, ctx);
    hipLaunchKernelGGL((k_gemm256<false>), dim3((D / 256) * (M / 256)), dim3(512), 0, stream,
                       ctx, woT, b_out, d_out, D, D / 256);
}

// Round 9
// 201.228 us; speedup vs baseline: 8.3700x; 1.0011x over previous
//
#include <hip/hip_runtime.h>
#include <hip/hip_bf16.h>

typedef short bf16x8 __attribute__((ext_vector_type(8)));
typedef float f32x4 __attribute__((ext_vector_type(4)));
typedef ushort ushort8_t __attribute__((ext_vector_type(8)));

__device__ __forceinline__ float bf2f(ushort u) {
    union { unsigned int i; float f; } c; c.i = ((unsigned int)u) << 16; return c.f;
}
__device__ __forceinline__ ushort f2bf(float f) {
    union { float f; unsigned int i; } c; c.f = f;
    unsigned int x = c.i;
    return (ushort)((x + 0x7fffu + ((x >> 16) & 1u)) >> 16);  // RNE
}

#define GLOAD_LDS16(g, l) __builtin_amdgcn_global_load_lds( \
    (const __attribute__((address_space(1))) unsigned int*)(g), \
    (__attribute__((address_space(3))) unsigned int*)(l), 16, 0, 0)

// ---------------- prep: fp32 -> bf16 (vectorized) ----------------
__global__ __launch_bounds__(256) void k_cvt_bf16(const float* __restrict__ in,
                                                  ushort* __restrict__ out, int n4) {
    int i = blockIdx.x * 256 + threadIdx.x;
    if (i < n4) {
        float4 v = ((const float4*)in)[i];
        ushort4 o;
        o.x = f2bf(v.x); o.y = f2bf(v.y); o.z = f2bf(v.z); o.w = f2bf(v.w);
        ((ushort4*)out)[i] = o;
    }
}

// ---------------- prep: [K][N] fp32 -> [N][K] bf16 ----------------
__global__ __launch_bounds__(256) void k_transpose_cvt(const float* __restrict__ in,
                                                       ushort* __restrict__ out,
                                                       int K, int N) {
    __shared__ float tile[32][33];
    int n0 = blockIdx.x * 32, k0 = blockIdx.y * 32;
    int tx = threadIdx.x, ty = threadIdx.y;  // blockDim (32,8)
    #pragma unroll
    for (int i = 0; i < 32; i += 8)
        tile[ty + i][tx] = in[(size_t)(k0 + ty + i) * N + n0 + tx];
    __syncthreads();
    #pragma unroll
    for (int i = 0; i < 32; i += 8)
        out[(size_t)(n0 + ty + i) * K + k0 + tx] = f2bf(tile[tx][ty + i]);
}

// ======== 256x256 GEMM, m201-faithful quadrant schedule (K=1024) =========
// 8 waves (2Mx4N), wave tile 128x64, BK=64 tiles as 2 k-half regions
// [256][32] (conflict-free swizzle, verified SQ_LDS_BANK_CONFLICT==0).
// m201 ports this round: (a) vmcnt(4) ONLY at ph4/ph8 (VM0 in tail);
// (b) quadrant MFMA: each phase = one C-quadrant (4m x 2n) x K=64 (2-deep
// kk chains), reads balanced 12/4/8/0 with dual B-reg sets bfrE/bfrO;
// (c) mid-phase {BAR; lgkmcnt(0); SB0} exactly as the m201 template.
// Stage slots ph1..8: A11(t+1),B11(t+1),B00(t+2),A00,B01,A01,B10(t+3),A10.
// WAR: every region staged >=1 barrier after its last reader (A(c,*) last
// read ph3/ph7, B(c,*) ph2/ph6).  RAW: VM4@ph4 certifies buf1 regions
// (B10,A10 prev ph7-8; A11,B11 ph1-2) for ph5-8; VM4@ph8 certifies buf0
// regions (B00..A01 ph3-6) for next ph1-3.  Unit-by-unit verified incl.
// prologue (12 loads, VM4) and tail (VM0@ph4).

#define LDSA(c,kk) (lds + (c)*65536 + (kk)*16384)
#define LDSB(c,kk) (lds + (c)*65536 + 32768 + (kk)*16384)
#define STAGE_A(c,kk,col) do { \
    GLOAD_LDS16(gA0 + (col), LDSA(c,kk) + wave*1024); \
    GLOAD_LDS16(gA1 + (col), LDSA(c,kk) + 8192 + wave*1024); } while(0)
#define STAGE_B(c,kk,col) do { \
    GLOAD_LDS16(gB0 + (col), LDSB(c,kk) + wave*1024); \
    GLOAD_LDS16(gB1 + (col), LDSB(c,kk) + 8192 + wave*1024); } while(0)

// A-frags for m-half MH: af[m*2+kk], rows wr*128 + (MH*4+m)*16 + r
#define READ_A(c,MH) do { \
    _Pragma("unroll") for (int m = 0; m < 4; ++m) { \
        af[m*2+0] = *(const bf16x8*)(LDSA(c,0) + aoff + (MH)*4096 + m*1024); \
        af[m*2+1] = *(const bf16x8*)(LDSA(c,1) + aoff + (MH)*4096 + m*1024); } } while(0)
// B-frags for n-half NH into reg set BR: BR[n*2+kk]
#define READ_B(c,NH,BR) do { \
    _Pragma("unroll") for (int n = 0; n < 2; ++n) { \
        BR[n*2+0] = *(const bf16x8*)(LDSB(c,0) + boff + (NH)*2048 + n*1024); \
        BR[n*2+1] = *(const bf16x8*)(LDSB(c,1) + boff + (NH)*2048 + n*1024); } } while(0)
// Quadrant MFMA: 16 MFMA = 8 acc frags x 2-deep kk chain
#define MFQ(MH,NH,BR) do { __builtin_amdgcn_s_setprio(1); \
    _Pragma("unroll") for (int m = 0; m < 4; ++m) \
    _Pragma("unroll") for (int n = 0; n < 2; ++n) { \
        f32x4 a = acc[(MH)*4+m][(NH)*2+n]; \
        a = __builtin_amdgcn_mfma_f32_16x16x32_bf16(af[m*2+0], BR[n*2+0], a, 0,0,0); \
        a = __builtin_amdgcn_mfma_f32_16x16x32_bf16(af[m*2+1], BR[n*2+1], a, 0,0,0); \
        acc[(MH)*4+m][(NH)*2+n] = a; } \
    __builtin_amdgcn_s_setprio(0); } while(0)

#define BAR __builtin_amdgcn_s_barrier()
#define SB0 __builtin_amdgcn_sched_barrier(0)
#define VM4 asm volatile("s_waitcnt vmcnt(4)")
#define VM0 asm volatile("s_waitcnt vmcnt(0)")

// m201 phase: [reads][stage][BAR][lgkm0][SB0][MFMA][vm?][BAR]
#define PH(reads, stage, mf, vm) do { reads; stage; BAR; \
    asm volatile("s_waitcnt lgkmcnt(0)"); SB0; mf; vm; BAR; } while(0)

#define ITERQ(kb, LAST) do { \
 /*1*/ PH({READ_A(0,0); READ_B(0,0,bfrE);}, STAGE_A(1,1,(kb)+96),              MFQ(0,0,bfrE), ); \
 /*2*/ PH({READ_B(0,1,bfrO);},              STAGE_B(1,1,(kb)+96),              MFQ(0,1,bfrO), ); \
 /*3*/ PH({READ_A(0,1);},                   if(!(LAST)) STAGE_B(0,0,(kb)+128), MFQ(1,1,bfrO), ); \
 /*4*/ PH({},                               if(!(LAST)) STAGE_A(0,0,(kb)+128), MFQ(1,0,bfrE), if(LAST) VM0; else VM4 ); \
 /*5*/ PH({READ_A(1,0); READ_B(1,0,bfrE);}, if(!(LAST)) STAGE_B(0,1,(kb)+160), MFQ(0,0,bfrE), ); \
 /*6*/ PH({READ_B(1,1,bfrO);},              if(!(LAST)) STAGE_A(0,1,(kb)+160), MFQ(0,1,bfrO), ); \
 /*7*/ PH({READ_A(1,1);},                   if(!(LAST)) STAGE_B(1,0,(kb)+192), MFQ(1,1,bfrO), ); \
 /*8*/ PH({},                               if(!(LAST)) STAGE_A(1,0,(kb)+192), MFQ(1,0,bfrE), if(!(LAST)) VM4 ); \
} while(0)

template<bool OUT_BF16>
__global__ __launch_bounds__(512, 2) void k_gemm256(const ushort* __restrict__ A,
                                                    const ushort* __restrict__ Bt,
                                                    const float* __restrict__ bias,
                                                    void* __restrict__ Cout,
                                                    int N, int NTN) {
    __shared__ __align__(16) char lds[131072];
    const int K = 1024;
    const int tid = threadIdx.x;
    const int wave = tid >> 6, lane = tid & 63;
    const int wr = wave >> 2, wc = wave & 3;
    const int r = lane & 15, q = lane >> 4;

    // bijective XCD swizzle (gridDim.x % 8 == 0)
    const int cpx = gridDim.x >> 3, wg = blockIdx.x;
    const int swz = (wg & 7) * cpx + (wg >> 3);
    const int tm = swz / NTN, tn = swz - tm * NTN;
    const int bm = tm * 256, bn = tn * 256;

    // staging lane pointers (source pre-swizzled: chunk ^= (row>>1)&3)
    const int srow = tid >> 2;                      // 0..127
    const int c16l = (tid & 3) ^ ((srow >> 1) & 3);
    const ushort* gA0 = A  + (size_t)(bm + srow) * K + c16l * 8;
    const ushort* gA1 = gA0 + (size_t)128 * K;
    const ushort* gB0 = Bt + (size_t)(bn + srow) * K + c16l * 8;
    const ushort* gB1 = gB0 + (size_t)128 * K;

    // swizzled ds_read offsets: chunk = q ^ ((row>>1)&3)
    const int chunkx = ((q ^ ((r >> 1) & 3)) << 4);
    const int aoff = (wr * 128 + r) * 64 + chunkx;
    const int boff = (wc * 64 + r) * 64 + chunkx;

    f32x4 acc[8][4];
    #pragma unroll
    for (int m = 0; m < 8; ++m)
        #pragma unroll
        for (int n = 0; n < 4; ++n)
            acc[m][n] = (f32x4){0.f, 0.f, 0.f, 0.f};
    bf16x8 af[8], bfrE[4], bfrO[4];

    // prologue: B00,A00,B01,A01 (tile0), B10,A10 (tile1) = 12 loads;
    // VM4 retires tile0's 8 (keeps {B10,A10}) -> steady-state entry.
    STAGE_B(0,0,0);  STAGE_A(0,0,0);
    STAGE_B(0,1,32); STAGE_A(0,1,32);
    STAGE_B(1,0,64); STAGE_A(1,0,64);
    VM4; BAR; SB0;

    #pragma unroll 1
    for (int i = 0; i < 7; ++i) { ITERQ(i * 128, 0); }
    ITERQ(896, 1);

    float* Cf = (float*)Cout;
    ushort* Cb = (ushort*)Cout;
    #pragma unroll
    for (int m = 0; m < 8; ++m) {
        int row0 = bm + wr * 128 + m * 16 + q * 4;
        #pragma unroll
        for (int n = 0; n < 4; ++n) {
            int col = bn + wc * 64 + n * 16 + r;
            float bv = bias[col];
            #pragma unroll
            for (int j = 0; j < 4; ++j) {
                float v = acc[m][n][j] + bv;
                if (OUT_BF16) Cb[(size_t)(row0 + j) * N + col] = f2bf(v);
                else          Cf[(size_t)(row0 + j) * N + col] = v;
            }
        }
    }
}

// ---------------- per-token head-mixing attention, MFMA, 1 wave/token ----
// qkv row layout: col = h*192 + {0..63 q, 64..127 k, 128..191 v}
// Swapped QK^T: S^T = mfma16x16x32(A=K, B=Q): lane(r=l&15,g=l>>4) holds
// S[qh=r][kh=4g+j].  Softmax over kh: in-lane (4) + shfl_xor 16,32.
// PV via mfma16x16x32 with K padded to 32: A-frag lane needs P[r][8g+j]
// (j=0..7, zero for g>=2) gathered with 8 shuffles; B-frag = V[kh][d].
__global__ __launch_bounds__(256) void k_attn_mfma(const ushort* __restrict__ qkv,
                                                   ushort* __restrict__ ctx) {
    const int lane = threadIdx.x & 63;
    const size_t tok = (size_t)blockIdx.x * 4 + (threadIdx.x >> 6);
    const ushort* row = qkv + tok * 3072;
    const int r = lane & 15, g = lane >> 4;

    bf16x8 ka[2], qb[2];
    #pragma unroll
    for (int c = 0; c < 2; ++c) {
        ka[c] = *(const bf16x8*)(row + r * 192 + 64 + c * 32 + g * 8);  // K[r][d]
        qb[c] = *(const bf16x8*)(row + r * 192 +      c * 32 + g * 8);  // Q[r][d]
    }
    f32x4 st = (f32x4){0.f, 0.f, 0.f, 0.f};
    st = __builtin_amdgcn_mfma_f32_16x16x32_bf16(ka[0], qb[0], st, 0, 0, 0);
    st = __builtin_amdgcn_mfma_f32_16x16x32_bf16(ka[1], qb[1], st, 0, 0, 0);

    float s[4];
    #pragma unroll
    for (int j = 0; j < 4; ++j) s[j] = st[j] * 0.125f;
    float m = fmaxf(fmaxf(s[0], s[1]), fmaxf(s[2], s[3]));
    m = fmaxf(m, __shfl_xor(m, 16));
    m = fmaxf(m, __shfl_xor(m, 32));
    float p[4], sum = 0.f;
    #pragma unroll
    for (int j = 0; j < 4; ++j) { p[j] = __expf(s[j] - m); sum += p[j]; }
    sum += __shfl_xor(sum, 16);
    sum += __shfl_xor(sum, 32);
    float inv = 1.f / sum;
    #pragma unroll
    for (int j = 0; j < 4; ++j) p[j] *= inv;

    // gather A-frag: lane needs P[r][8g+j]; source lane r+32g (j0-3), +16 (j4-7)
    const bool gok = (g < 2);
    const int src0 = (r + 32 * g) & 63, src1 = (src0 + 16) & 63;
    bf16x8 pa;
    #pragma unroll
    for (int j = 0; j < 4; ++j) {
        float a0 = __shfl(p[j], src0, 64);
        float a1 = __shfl(p[j], src1, 64);
        pa[j]     = (short)(gok ? f2bf(a0) : (ushort)0);
        pa[4 + j] = (short)(gok ? f2bf(a1) : (ushort)0);
    }

    #pragma unroll
    for (int db = 0; db < 4; ++db) {
        bf16x8 vb;
        #pragma unroll
        for (int j = 0; j < 8; ++j)
            vb[j] = (short)(gok ? row[(g * 8 + j) * 192 + 128 + db * 16 + r] : (ushort)0);
        f32x4 o = (f32x4){0.f, 0.f, 0.f, 0.f};
        o = __builtin_amdgcn_mfma_f32_16x16x32_bf16(pa, vb, o, 0, 0, 0);
        #pragma unroll
        for (int j = 0; j < 4; ++j)
            ctx[tok * 1024 + (4 * g + j) * 64 + db * 16 + r] = f2bf(o[j]);
    }
}

extern "C" void kernel_launch(void* const* d_in, const int* in_sizes, int n_in,
                              void* d_out, int out_size, void* d_ws, size_t ws_size,
                              hipStream_t stream) {
    const float* x     = (const float*)d_in[0];
    const float* W_qkv = (const float*)d_in[1];
    const float* b_qkv = (const float*)d_in[2];
    const float* W_out = (const float*)d_in[3];
    const float* b_out = (const float*)d_in[4];

    const int M = 16384, D = 1024, N3 = 3072;

    ushort* xb   = (ushort*)d_ws;
    ushort* wqkT = xb + (size_t)M * D;
    ushort* woT  = wqkT + (size_t)N3 * D;
    ushort* qkv  = woT + (size_t)D * D;
    ushort* ctx  = xb;  // xb dead after GEMM1; reuse for context

    hipLaunchKernelGGL(k_cvt_bf16, dim3((M * D / 4 + 255) / 256), dim3(256), 0, stream,
                       x, xb, M * D / 4);
    hipLaunchKernelGGL(k_transpose_cvt, dim3(N3 / 32, D / 32), dim3(32, 8), 0, stream,
                       W_qkv, wqkT, D, N3);
    hipLaunchKernelGGL(k_transpose_cvt, dim3(D / 32, D / 32), dim3(32, 8), 0, stream,
                       W_out, woT, D, D);
    hipLaunchKernelGGL((k_gemm256<true>), dim3((N3 / 256) * (M / 256)), dim3(512), 0, stream,
                       xb, wqkT, b_qkv, (void*)qkv, N3, N3 / 256);
    hipLaunchKernelGGL(k_attn_mfma, dim3(M / 4), dim3(256), 0, stream, qkv, ctx);
    hipLaunchKernelGGL((k_gemm256<false>), dim3((D / 256) * (M / 256)), dim3(512), 0, stream,
                       ctx, woT, b_out, d_out, D, D / 256);
}